// Round 1
// baseline (606.411 us; speedup 1.0000x reference)
//
#include <hip/hip_runtime.h>
#include <math.h>

// Spectral_Filter_Transform: per-channel rfft -> keep top-16 |X| bins -> irfft
// (= sum of 16 cosines) -> flip-pad 12 -> 25-tap periodic-Hamming average.
// One block (256 threads) per (b,f) channel; 4096 blocks total.

#define NN     4096      // T, FFT length
#define LOGN   12
#define NT     256       // threads per block
#define EPT    16        // NN / NT
#define NFREQ  2049      // rfft bins
#define KTOP   16
#define WSZ    25
#define HALFW  12
#define FDIM   128
#define TWO_PI 6.283185307179586f

// skewed LDS index for the conv phase: breaks stride-16 (32-way) bank conflicts
// down to a free 2-way pattern.
__device__ __forceinline__ int swz(int a) { return a + (a >> 5); }

__global__ __launch_bounds__(NT, 3)
void spectral_filter_kernel(const float* __restrict__ x, float* __restrict__ out)
{
    __shared__ float s_re[NN + (NN >> 5)];  // FFT real; later skewed xf buffer
    __shared__ float s_im[NN];              // FFT imag
    __shared__ float s_tw[NN];              // cos[0..2047], sin[2048..4095]; reused as |X|^2
    __shared__ float s_w[WSZ];
    __shared__ float s_wsum;
    __shared__ float s_rv[NT / 64];
    __shared__ int   s_ri[NT / 64];
    __shared__ int   s_kf[KTOP];
    __shared__ float s_kr[KTOP];
    __shared__ float s_ki[KTOP];

    const int tid = threadIdx.x;
    const int c   = blockIdx.x;
    const int b   = c >> 7;           // c / 128
    const int f   = c & (FDIM - 1);   // c % 128
    const size_t base = (size_t)b * NN * FDIM + f;

    // periodic hamming window (matches torch.hamming_window(25))
    if (tid < WSZ)
        s_w[tid] = 0.54f - 0.46f * cosf(TWO_PI * (float)tid / (float)WSZ);

    // twiddle table: e^{-2*pi*i*q/N}, q in [0, 2048)
    for (int i = tid; i < NN / 2; i += NT) {
        float sn, cs;
        sincosf(-TWO_PI * (float)i / (float)NN, &sn, &cs);
        s_tw[i]          = cs;
        s_tw[i + NN / 2] = sn;
    }

    // load channel in bit-reversed order (imag = 0)
    #pragma unroll
    for (int i = 0; i < EPT; ++i) {
        int j = tid + i * NT;
        int t = (int)(__brev((unsigned)j) >> (32 - LOGN));
        s_re[j] = x[base + (size_t)t * FDIM];
        s_im[j] = 0.0f;
    }
    __syncthreads();

    if (tid == 0) {   // sum(w) in fp32, matching jnp.sum(w)
        float a = 0.0f;
        for (int i = 0; i < WSZ; ++i) a += s_w[i];
        s_wsum = a;
    }

    // in-place radix-2 DIT FFT, natural-order output = forward DFT (e^{-i...})
    for (int s = 1; s <= LOGN; ++s) {
        const int half = 1 << (s - 1);
        const int tsh  = LOGN - s;
        #pragma unroll
        for (int i = 0; i < EPT / 2; ++i) {
            int j  = tid + i * NT;             // butterfly id, 0..2047
            int p  = j & (half - 1);
            int i0 = ((j >> (s - 1)) << s) + p;
            int i1 = i0 + half;
            int q  = p << tsh;
            float wr = s_tw[q], wi = s_tw[q + NN / 2];
            float ar = s_re[i0], ai = s_im[i0];
            float br = s_re[i1], bi = s_im[i1];
            float tr = br * wr - bi * wi;
            float ti = br * wi + bi * wr;
            s_re[i0] = ar + tr;  s_im[i0] = ai + ti;
            s_re[i1] = ar - tr;  s_im[i1] = ai - ti;
        }
        __syncthreads();
    }

    // squared magnitudes of rfft bins into dead twiddle buffer
    for (int i = tid; i < NFREQ; i += NT) {
        float rr = s_re[i], ii = s_im[i];
        s_tw[i] = rr * rr + ii * ii;
    }
    __syncthreads();

    // 16 rounds of block-wide argmax (lower index wins ties, like lax.top_k)
    for (int r = 0; r < KTOP; ++r) {
        float best = -1.0f; int bidx = 0x7fffffff;
        for (int i = tid; i < NFREQ; i += NT) {
            float v = s_tw[i];
            if (v > best) { best = v; bidx = i; }   // ascending scan keeps lowest idx on tie
        }
        #pragma unroll
        for (int off = 32; off > 0; off >>= 1) {
            float ov = __shfl_down(best, off);
            int   oi = __shfl_down(bidx, off);
            if (ov > best || (ov == best && oi < bidx)) { best = ov; bidx = oi; }
        }
        const int wid = tid >> 6;
        if ((tid & 63) == 0) { s_rv[wid] = best; s_ri[wid] = bidx; }
        __syncthreads();
        if (tid == 0) {
            float bv = s_rv[0]; int bx = s_ri[0];
            #pragma unroll
            for (int w2 = 1; w2 < NT / 64; ++w2) {
                float ov = s_rv[w2]; int oi = s_ri[w2];
                if (ov > bv || (ov == bv && oi < bx)) { bv = ov; bx = oi; }
            }
            s_kf[r] = bx;
            s_kr[r] = s_re[bx];
            s_ki[r] = s_im[bx];
            s_tw[bx] = -1.0f;    // exclude from later rounds
        }
        __syncthreads();
    }

    // irfft of 16-bin spectrum: xf[t] = (1/N) * sum_j sc_j*(vr_j*cos - vi_j*sin)
    // phase-rotation recurrence over 16 contiguous t per thread; integer phase
    // reduction mod N keeps sincosf arguments small/exact.
    const int t0 = tid * EPT;
    float xf[EPT];
    #pragma unroll
    for (int i = 0; i < EPT; ++i) xf[i] = 0.0f;

    for (int r = 0; r < KTOP; ++r) {
        const int fj = s_kf[r];
        float vr = s_kr[r], vi = s_ki[r];
        float sc = 2.0f;
        if (fj == 0 || fj == NN / 2) { sc = 1.0f; vi = 0.0f; }  // DC/Nyquist: real only
        vr *= sc; vi *= sc;
        const int ph0 = (fj * t0) & (NN - 1);
        float c0, s0, dc, ds;
        sincosf((float)ph0 * (TWO_PI / (float)NN), &s0, &c0);
        sincosf((float)fj  * (TWO_PI / (float)NN), &ds, &dc);
        float cr = c0, ci = s0;
        #pragma unroll
        for (int i = 0; i < EPT; ++i) {
            xf[i] += vr * cr - vi * ci;
            float nc = cr * dc - ci * ds;
            ci = ci * dc + cr * ds;
            cr = nc;
        }
    }
    __syncthreads();           // all spectrum reads of s_re are complete

    #pragma unroll
    for (int i = 0; i < EPT; ++i)
        s_re[swz(t0 + i)] = xf[i] * (1.0f / (float)NN);
    __syncthreads();

    // flip-padded 25-tap correlation: out[t] = sum_i xp[t+i]*w[i] / sum(w)
    // xp[j] = xf[m], m = j-12 mirrored at both ends.
    float win[EPT + WSZ - 1];  // 40 consecutive xp values for this thread
    #pragma unroll
    for (int i = 0; i < EPT + WSZ - 1; ++i) {
        int a = t0 + i - HALFW;
        if (a < 0)        a = -1 - a;            // left flip:  xf[11-j]
        else if (a >= NN) a = 2 * NN - 1 - a;    // right flip: xf[8203-j-12]
        win[i] = s_re[swz(a)];
    }

    const float rinv = 1.0f / s_wsum;
    float acc[EPT];
    #pragma unroll
    for (int t = 0; t < EPT; ++t) acc[t] = 0.0f;
    #pragma unroll
    for (int i = 0; i < WSZ; ++i) {
        const float wv = s_w[i];
        #pragma unroll
        for (int t = 0; t < EPT; ++t) acc[t] += win[t + i] * wv;
    }
    #pragma unroll
    for (int t = 0; t < EPT; ++t)
        out[base + (size_t)(t0 + t) * FDIM] = acc[t] * rinv;
}

extern "C" void kernel_launch(void* const* d_in, const int* in_sizes, int n_in,
                              void* d_out, int out_size, void* d_ws, size_t ws_size,
                              hipStream_t stream)
{
    const float* x = (const float*)d_in[0];
    float* out = (float*)d_out;
    // window_size (d_in[1]) and k (d_in[2]) are fixed by the problem: 25, 16.
    spectral_filter_kernel<<<dim3(32 * FDIM), dim3(NT), 0, stream>>>(x, out);
}

// Round 2
// 451.136 us; speedup vs baseline: 1.3442x; 1.3442x over previous
//
#include <hip/hip_runtime.h>
#include <math.h>

// Spectral_Filter_Transform: per-channel rfft -> keep top-16 |X| bins -> irfft
// (= sum of 16 cosines) -> flip-pad 12 -> 25-tap periodic-Hamming average.
//
// 3-kernel pipeline for coalescing:
//   K1: transpose x (B,T,F) -> ws (B,F,T)          [tiled, coalesced]
//   K2: per-channel DIF FFT + topk + recon + conv, in-place on ws
//   K3: transpose ws (B,F,T) -> out (B,T,F)
// Falls back to the single-kernel (round-1) version if ws is too small.

#define NN     4096
#define LOGN   12
#define NT     256
#define EPT    16      // NN / NT
#define KTOP   16
#define WSZ    25
#define HALFW  12
#define FDIM   128
#define BATCH  32
#define TWO_PI 6.283185307179586f

// skew: breaks stride-16 / stride-32 LDS bank patterns down to <=2-way (free)
__device__ __forceinline__ int swz(int a) { return a + (a >> 5); }

// ---------------------------------------------------------------- transpose
// in: R x C (per batch) -> out: C x R. R, C multiples of 64. grid(C/64, R/64, B)
__global__ __launch_bounds__(256)
void transpose_kernel(const float* __restrict__ in, float* __restrict__ out,
                      int R, int C)
{
    __shared__ float tile[64][65];
    const int b = blockIdx.z;
    const float* pin = in  + (size_t)b * R * C;
    float*       pout = out + (size_t)b * R * C;
    const int r0 = blockIdx.y * 64, c0 = blockIdx.x * 64;
    const int tx = threadIdx.x & 63, ty = threadIdx.x >> 6;
    #pragma unroll
    for (int i = 0; i < 16; ++i) {
        int r = ty + i * 4;
        tile[r][tx] = pin[(size_t)(r0 + r) * C + (c0 + tx)];
    }
    __syncthreads();
    #pragma unroll
    for (int i = 0; i < 16; ++i) {
        int r = ty + i * 4;
        pout[(size_t)(c0 + r) * R + (r0 + tx)] = tile[tx][r];
    }
}

// ---------------------------------------------------------------- main kernel
// One block per channel; channel data contiguous at ws + c*NN. In-place.
__global__ __launch_bounds__(NT, 3)
void spectral_fft_kernel(float* __restrict__ ws)
{
    __shared__ float s_re[NN + (NN >> 5)];   // FFT real / skewed xf buffer
    __shared__ float s_im[NN + (NN >> 5)];   // FFT imag / skewed conv-out staging
    __shared__ float s_tw[NN + (NN >> 5)];   // skewed twiddles; reused as |X|^2
    __shared__ float s_w[WSZ];
    __shared__ float s_wsum;
    __shared__ float s_rv[NT / 64];
    __shared__ int   s_ri[NT / 64];
    __shared__ int   s_kf[KTOP];
    __shared__ float s_kr[KTOP];
    __shared__ float s_ki[KTOP];

    const int tid = threadIdx.x;
    float* chan = ws + (size_t)blockIdx.x * NN;

    if (tid < WSZ)
        s_w[tid] = 0.54f - 0.46f * cosf(TWO_PI * (float)tid / (float)WSZ);

    // skewed twiddle table: cos at swz(q), sin at swz(q+2048), q in [0,2048)
    for (int i = tid; i < NN / 2; i += NT) {
        float sn, cs;
        sincosf(-TWO_PI * (float)i / (float)NN, &sn, &cs);
        s_tw[swz(i)]          = cs;
        s_tw[swz(i + NN / 2)] = sn;
    }

    // coalesced float4 load of the contiguous channel, natural order
    const float4* ch4 = (const float4*)chan;
    float4 ld[4];
    #pragma unroll
    for (int i = 0; i < 4; ++i) ld[i] = ch4[tid + i * NT];
    #pragma unroll
    for (int i = 0; i < 4; ++i) {
        int a = (tid + i * NT) * 4;
        s_re[a] = ld[i].x; s_re[a + 1] = ld[i].y;
        s_re[a + 2] = ld[i].z; s_re[a + 3] = ld[i].w;
        s_im[a] = 0.0f; s_im[a + 1] = 0.0f; s_im[a + 2] = 0.0f; s_im[a + 3] = 0.0f;
    }
    __syncthreads();

    if (tid == 0) {   // sum(w) sequential fp32, matching jnp.sum(w)
        float a = 0.0f;
        for (int i = 0; i < WSZ; ++i) a += s_w[i];
        s_wsum = a;
    }

    // in-place radix-2 DIF (Gentleman-Sande): natural in -> bit-reversed out.
    // z_final[j] = X[bitrev12(j)], X = forward DFT with e^{-i...}
    for (int s = LOGN; s >= 1; --s) {
        const int half = 1 << (s - 1);
        const int tsh  = LOGN - s;
        #pragma unroll
        for (int i = 0; i < EPT / 2; ++i) {
            int j  = tid + i * NT;
            int p  = j & (half - 1);
            int i0 = ((j >> (s - 1)) << s) + p;
            int i1 = i0 + half;
            int q  = p << tsh;
            float wr = s_tw[swz(q)], wi = s_tw[swz(q + NN / 2)];
            float ar = s_re[i0], ai = s_im[i0];
            float br = s_re[i1], bi = s_im[i1];
            s_re[i0] = ar + br;  s_im[i0] = ai + bi;
            float tr = ar - br, ti = ai - bi;
            s_re[i1] = tr * wr - ti * wi;
            s_im[i1] = tr * wi + ti * wr;
        }
        __syncthreads();
    }

    // squared magnitudes over the bit-reversed spectrum; keep only positions
    // whose true bin k = bitrev(i) is a valid rfft bin (k <= N/2); each bin
    // 0..2048 appears exactly once (bitrev is a bijection).
    for (int i = tid; i < NN; i += NT) {
        int k = (int)(__brev((unsigned)i) >> (32 - LOGN));
        float rr = s_re[i], ii = s_im[i];
        s_tw[i] = (k <= NN / 2) ? (rr * rr + ii * ii) : -2.0f;
    }
    __syncthreads();

    // 16 rounds of block-wide argmax
    for (int r = 0; r < KTOP; ++r) {
        float best = -1.0f; int bidx = 0x7fffffff;
        for (int i = tid; i < NN; i += NT) {
            float v = s_tw[i];
            if (v > best) { best = v; bidx = i; }
        }
        #pragma unroll
        for (int off = 32; off > 0; off >>= 1) {
            float ov = __shfl_down(best, off);
            int   oi = __shfl_down(bidx, off);
            if (ov > best || (ov == best && oi < bidx)) { best = ov; bidx = oi; }
        }
        const int wid = tid >> 6;
        if ((tid & 63) == 0) { s_rv[wid] = best; s_ri[wid] = bidx; }
        __syncthreads();
        if (tid == 0) {
            float bv = s_rv[0]; int bx = s_ri[0];
            #pragma unroll
            for (int w2 = 1; w2 < NT / 64; ++w2) {
                float ov = s_rv[w2]; int oi = s_ri[w2];
                if (ov > bv || (ov == bv && oi < bx)) { bv = ov; bx = oi; }
            }
            s_kf[r] = (int)(__brev((unsigned)bx) >> (32 - LOGN));  // true frequency
            s_kr[r] = s_re[bx];
            s_ki[r] = s_im[bx];
            s_tw[bx] = -3.0f;     // exclude from later rounds
        }
        __syncthreads();
    }

    // irfft of 16-bin spectrum: xf[t] = (1/N) * sum_j sc_j*(vr_j*cos - vi_j*sin)
    const int t0 = tid * EPT;
    float xf[EPT];
    #pragma unroll
    for (int i = 0; i < EPT; ++i) xf[i] = 0.0f;

    for (int r = 0; r < KTOP; ++r) {
        const int fj = s_kf[r];
        float vr = s_kr[r], vi = s_ki[r];
        float sc = 2.0f;
        if (fj == 0 || fj == NN / 2) { sc = 1.0f; vi = 0.0f; }  // DC/Nyquist
        vr *= sc; vi *= sc;
        const int ph0 = (fj * t0) & (NN - 1);   // exact integer phase mod N
        float c0, s0, dc, ds;
        sincosf((float)ph0 * (TWO_PI / (float)NN), &s0, &c0);
        sincosf((float)fj  * (TWO_PI / (float)NN), &ds, &dc);
        float cr = c0, ci = s0;
        #pragma unroll
        for (int i = 0; i < EPT; ++i) {
            xf[i] += vr * cr - vi * ci;
            float nc = cr * dc - ci * ds;
            ci = ci * dc + cr * ds;
            cr = nc;
        }
    }

    #pragma unroll
    for (int i = 0; i < EPT; ++i)
        s_re[swz(t0 + i)] = xf[i] * (1.0f / (float)NN);
    __syncthreads();

    // flip-padded 25-tap correlation
    float win[EPT + WSZ - 1];
    #pragma unroll
    for (int i = 0; i < EPT + WSZ - 1; ++i) {
        int a = t0 + i - HALFW;
        if (a < 0)        a = -1 - a;
        else if (a >= NN) a = 2 * NN - 1 - a;
        win[i] = s_re[swz(a)];
    }

    const float rinv = 1.0f / s_wsum;
    float acc[EPT];
    #pragma unroll
    for (int t = 0; t < EPT; ++t) acc[t] = 0.0f;
    #pragma unroll
    for (int i = 0; i < WSZ; ++i) {
        const float wv = s_w[i];
        #pragma unroll
        for (int t = 0; t < EPT; ++t) acc[t] += win[t + i] * wv;
    }

    // stage conv output in (skewed) LDS so the global write is float4-coalesced
    #pragma unroll
    for (int t = 0; t < EPT; ++t) s_im[swz(t0 + t)] = acc[t] * rinv;
    __syncthreads();

    float4* ch4w = (float4*)chan;
    #pragma unroll
    for (int i = 0; i < 4; ++i) {
        int a  = (tid + i * NT) * 4;
        int sa = swz(a);       // a is 4-aligned => a..a+3 share one 32-block
        float4 v = { s_im[sa], s_im[sa + 1], s_im[sa + 2], s_im[sa + 3] };
        ch4w[tid + i * NT] = v;
    }
}

// ---------------------------------------------------------------- fallback
// Round-1 single-kernel version (strided I/O), used only if ws is too small.
__global__ __launch_bounds__(NT, 3)
void spectral_filter_fallback(const float* __restrict__ x, float* __restrict__ out)
{
    __shared__ float s_re[NN + (NN >> 5)];
    __shared__ float s_im[NN];
    __shared__ float s_tw[NN];
    __shared__ float s_w[WSZ];
    __shared__ float s_wsum;
    __shared__ float s_rv[NT / 64];
    __shared__ int   s_ri[NT / 64];
    __shared__ int   s_kf[KTOP];
    __shared__ float s_kr[KTOP];
    __shared__ float s_ki[KTOP];

    const int tid = threadIdx.x;
    const int c   = blockIdx.x;
    const int b   = c >> 7;
    const int f   = c & (FDIM - 1);
    const size_t base = (size_t)b * NN * FDIM + f;

    if (tid < WSZ)
        s_w[tid] = 0.54f - 0.46f * cosf(TWO_PI * (float)tid / (float)WSZ);

    for (int i = tid; i < NN / 2; i += NT) {
        float sn, cs;
        sincosf(-TWO_PI * (float)i / (float)NN, &sn, &cs);
        s_tw[i]          = cs;
        s_tw[i + NN / 2] = sn;
    }

    #pragma unroll
    for (int i = 0; i < EPT; ++i) {
        int j = tid + i * NT;
        int t = (int)(__brev((unsigned)j) >> (32 - LOGN));
        s_re[j] = x[base + (size_t)t * FDIM];
        s_im[j] = 0.0f;
    }
    __syncthreads();

    if (tid == 0) {
        float a = 0.0f;
        for (int i = 0; i < WSZ; ++i) a += s_w[i];
        s_wsum = a;
    }

    for (int s = 1; s <= LOGN; ++s) {
        const int half = 1 << (s - 1);
        const int tsh  = LOGN - s;
        #pragma unroll
        for (int i = 0; i < EPT / 2; ++i) {
            int j  = tid + i * NT;
            int p  = j & (half - 1);
            int i0 = ((j >> (s - 1)) << s) + p;
            int i1 = i0 + half;
            int q  = p << tsh;
            float wr = s_tw[q], wi = s_tw[q + NN / 2];
            float ar = s_re[i0], ai = s_im[i0];
            float br = s_re[i1], bi = s_im[i1];
            float tr = br * wr - bi * wi;
            float ti = br * wi + bi * wr;
            s_re[i0] = ar + tr;  s_im[i0] = ai + ti;
            s_re[i1] = ar - tr;  s_im[i1] = ai - ti;
        }
        __syncthreads();
    }

    for (int i = tid; i < NN / 2 + 1; i += NT) {
        float rr = s_re[i], ii = s_im[i];
        s_tw[i] = rr * rr + ii * ii;
    }
    __syncthreads();

    for (int r = 0; r < KTOP; ++r) {
        float best = -1.0f; int bidx = 0x7fffffff;
        for (int i = tid; i < NN / 2 + 1; i += NT) {
            float v = s_tw[i];
            if (v > best) { best = v; bidx = i; }
        }
        #pragma unroll
        for (int off = 32; off > 0; off >>= 1) {
            float ov = __shfl_down(best, off);
            int   oi = __shfl_down(bidx, off);
            if (ov > best || (ov == best && oi < bidx)) { best = ov; bidx = oi; }
        }
        const int wid = tid >> 6;
        if ((tid & 63) == 0) { s_rv[wid] = best; s_ri[wid] = bidx; }
        __syncthreads();
        if (tid == 0) {
            float bv = s_rv[0]; int bx = s_ri[0];
            #pragma unroll
            for (int w2 = 1; w2 < NT / 64; ++w2) {
                float ov = s_rv[w2]; int oi = s_ri[w2];
                if (ov > bv || (ov == bv && oi < bx)) { bv = ov; bx = oi; }
            }
            s_kf[r] = bx;
            s_kr[r] = s_re[bx];
            s_ki[r] = s_im[bx];
            s_tw[bx] = -1.0f;
        }
        __syncthreads();
    }

    const int t0 = tid * EPT;
    float xf[EPT];
    #pragma unroll
    for (int i = 0; i < EPT; ++i) xf[i] = 0.0f;

    for (int r = 0; r < KTOP; ++r) {
        const int fj = s_kf[r];
        float vr = s_kr[r], vi = s_ki[r];
        float sc = 2.0f;
        if (fj == 0 || fj == NN / 2) { sc = 1.0f; vi = 0.0f; }
        vr *= sc; vi *= sc;
        const int ph0 = (fj * t0) & (NN - 1);
        float c0, s0, dc, ds;
        sincosf((float)ph0 * (TWO_PI / (float)NN), &s0, &c0);
        sincosf((float)fj  * (TWO_PI / (float)NN), &ds, &dc);
        float cr = c0, ci = s0;
        #pragma unroll
        for (int i = 0; i < EPT; ++i) {
            xf[i] += vr * cr - vi * ci;
            float nc = cr * dc - ci * ds;
            ci = ci * dc + cr * ds;
            cr = nc;
        }
    }
    __syncthreads();

    #pragma unroll
    for (int i = 0; i < EPT; ++i)
        s_re[swz(t0 + i)] = xf[i] * (1.0f / (float)NN);
    __syncthreads();

    float win[EPT + WSZ - 1];
    #pragma unroll
    for (int i = 0; i < EPT + WSZ - 1; ++i) {
        int a = t0 + i - HALFW;
        if (a < 0)        a = -1 - a;
        else if (a >= NN) a = 2 * NN - 1 - a;
        win[i] = s_re[swz(a)];
    }

    const float rinv = 1.0f / s_wsum;
    float acc[EPT];
    #pragma unroll
    for (int t = 0; t < EPT; ++t) acc[t] = 0.0f;
    #pragma unroll
    for (int i = 0; i < WSZ; ++i) {
        const float wv = s_w[i];
        #pragma unroll
        for (int t = 0; t < EPT; ++t) acc[t] += win[t + i] * wv;
    }
    #pragma unroll
    for (int t = 0; t < EPT; ++t)
        out[base + (size_t)(t0 + t) * FDIM] = acc[t] * rinv;
}

extern "C" void kernel_launch(void* const* d_in, const int* in_sizes, int n_in,
                              void* d_out, int out_size, void* d_ws, size_t ws_size,
                              hipStream_t stream)
{
    const float* x = (const float*)d_in[0];
    float* out = (float*)d_out;
    const size_t need = (size_t)BATCH * FDIM * NN * sizeof(float);
    if (ws_size >= need) {
        float* ws = (float*)d_ws;
        // K1: x (B, T=4096, F=128) -> ws (B, F, T)
        transpose_kernel<<<dim3(FDIM / 64, NN / 64, BATCH), 256, 0, stream>>>(x, ws, NN, FDIM);
        // K2: per-channel pipeline, in place on ws
        spectral_fft_kernel<<<dim3(BATCH * FDIM), NT, 0, stream>>>(ws);
        // K3: ws (B, F=128, T=4096) -> out (B, T, F)
        transpose_kernel<<<dim3(NN / 64, FDIM / 64, BATCH), 256, 0, stream>>>(ws, out, FDIM, NN);
    } else {
        spectral_filter_fallback<<<dim3(BATCH * FDIM), NT, 0, stream>>>(x, out);
    }
}

// Round 3
// 394.263 us; speedup vs baseline: 1.5381x; 1.1443x over previous
//
#include <hip/hip_runtime.h>
#include <math.h>

// Spectral_Filter_Transform: per-channel rfft -> keep top-16 |X| bins -> irfft
// (= sum of 16 cosines) -> flip-pad 12 -> 25-tap periodic-Hamming average.
//
// 3-kernel pipeline:
//   K1: transpose x (B,T,F) -> ws (B,F,T)          [float4 tiled]
//   K2: per-channel radix-4 DIF FFT + register top-k + table-lookup recon + conv
//   K3: transpose ws (B,F,T) -> out (B,T,F)
// Fallback single-kernel version if ws is too small.

#define NN     4096
#define LOGN   12
#define NT     256
#define EPT    16      // NN / NT
#define KTOP   16
#define WSZ    25
#define HALFW  12
#define FDIM   128
#define BATCH  32
#define TWO_PI 6.283185307179586f

// skew: spreads power-of-2 LDS strides across banks; preserves float4 groups
// (4-aligned a: swz(a)+d == swz(a+d) for d<4).
__device__ __forceinline__ int swz(int a) { return a + (a >> 5); }

// digit-reverse base-4 of a 12-bit index (self-inverse)
__device__ __forceinline__ int rev4(int j) {
    unsigned r = __brev((unsigned)j) >> 20;          // 12-bit bit reverse
    return (int)(((r & 0x555u) << 1) | ((r >> 1) & 0x555u));
}

// ---------------------------------------------------------------- transpose
// in: R x C (per batch) -> out: C x R. R, C multiples of 64. grid(C/64, R/64, B)
__global__ __launch_bounds__(256)
void transpose_kernel(const float* __restrict__ in, float* __restrict__ out,
                      int R, int C)
{
    __shared__ float tile[64][65];
    const int b = blockIdx.z;
    const float* pin  = in  + (size_t)b * R * C;
    float*       pout = out + (size_t)b * R * C;
    const int r0 = blockIdx.y * 64, c0 = blockIdx.x * 64;
    const int tc4 = (threadIdx.x & 15) * 4;
    const int tr  = threadIdx.x >> 4;
    #pragma unroll
    for (int i = 0; i < 4; ++i) {
        int r = tr + i * 16;
        float4 v = *(const float4*)&pin[(size_t)(r0 + r) * C + c0 + tc4];
        tile[r][tc4 + 0] = v.x; tile[r][tc4 + 1] = v.y;
        tile[r][tc4 + 2] = v.z; tile[r][tc4 + 3] = v.w;
    }
    __syncthreads();
    #pragma unroll
    for (int i = 0; i < 4; ++i) {
        int r = tr + i * 16;     // output row = original column block offset
        float4 v;
        v.x = tile[tc4 + 0][r]; v.y = tile[tc4 + 1][r];
        v.z = tile[tc4 + 2][r]; v.w = tile[tc4 + 3][r];
        *(float4*)&pout[(size_t)(c0 + r) * R + r0 + tc4] = v;
    }
}

// ---------------------------------------------------------------- main kernel
// One block per channel; channel contiguous at ws + c*NN. In-place.
__global__ __launch_bounds__(NT, 3)
void spectral_fft_kernel(float* __restrict__ ws)
{
    __shared__ float s_re[NN + (NN >> 5)];   // skewed FFT real / xf buffer
    __shared__ float s_im[NN + (NN >> 5)];   // skewed FFT imag / conv-out staging
    __shared__ float s_tw[NN + (NN >> 5)];   // skewed: cos(2πq/N) at swz(q),
                                             //        -sin(2πq/N) at swz(q+2048)
    __shared__ float s_w[WSZ];
    __shared__ float s_wsum;
    __shared__ float s_rv[NT / 64];
    __shared__ int   s_rk[NT / 64];
    __shared__ int   s_kf[KTOP];
    __shared__ float s_kr[KTOP];
    __shared__ float s_ki[KTOP];

    const int tid = threadIdx.x;
    float* chan = ws + (size_t)blockIdx.x * NN;

    if (tid < WSZ)
        s_w[tid] = 0.54f - 0.46f * cosf(TWO_PI * (float)tid / (float)WSZ);

    for (int i = tid; i < NN / 2; i += NT) {
        float sn, cs;
        sincosf(-TWO_PI * (float)i / (float)NN, &sn, &cs);
        s_tw[swz(i)]          = cs;   //  cos(2πi/N)
        s_tw[swz(i + NN / 2)] = sn;   // -sin(2πi/N)
    }

    // coalesced float4 load, natural order, into skewed LDS
    const float4* ch4 = (const float4*)chan;
    float4 ld[4];
    #pragma unroll
    for (int i = 0; i < 4; ++i) ld[i] = ch4[tid + i * NT];
    #pragma unroll
    for (int i = 0; i < 4; ++i) {
        int a  = (tid + i * NT) * 4;
        int sa = swz(a);
        s_re[sa] = ld[i].x; s_re[sa + 1] = ld[i].y;
        s_re[sa + 2] = ld[i].z; s_re[sa + 3] = ld[i].w;
        s_im[sa] = 0.0f; s_im[sa + 1] = 0.0f; s_im[sa + 2] = 0.0f; s_im[sa + 3] = 0.0f;
    }
    __syncthreads();

    if (tid == 0) {   // sequential fp32 sum, matching jnp.sum(w)
        float a = 0.0f;
        for (int i = 0; i < WSZ; ++i) a += s_w[i];
        s_wsum = a;
    }

    // radix-4 DIF FFT (forward, e^{-i}), natural in -> base-4 digit-reversed out.
    // Stage s: L = N/4^s, Q = L/4; result r of each butterfly -> slot base + r*Q,
    // twiddles w^p, w^2p (from table), w^3p = w^p * w^2p.
    #pragma unroll
    for (int s = 0; s < 5; ++s) {
        const int Lsh = LOGN - 2 * s;       // L = 1 << Lsh
        const int Q   = 1 << (Lsh - 2);
        #pragma unroll
        for (int u = 0; u < 4; ++u) {
            int j = tid + u * NT;           // butterfly id 0..1023
            int p = j & (Q - 1);
            int g = j >> (Lsh - 2);
            int base = (g << Lsh) + p;
            int q1 = p << (2 * s);          // < 1024
            float w1r = s_tw[swz(q1)],     w1i = s_tw[swz(q1 + NN / 2)];
            float w2r = s_tw[swz(2 * q1)], w2i = s_tw[swz(2 * q1 + NN / 2)];
            float w3r = w1r * w2r - w1i * w2i;
            float w3i = w1r * w2i + w1i * w2r;
            int i0 = swz(base), i1 = swz(base + Q);
            int i2 = swz(base + 2 * Q), i3 = swz(base + 3 * Q);
            float ar = s_re[i0], ai = s_im[i0], br = s_re[i1], bi = s_im[i1];
            float cr = s_re[i2], ci = s_im[i2], dr = s_re[i3], di = s_im[i3];
            float t0r = ar + cr, t0i = ai + ci, t1r = ar - cr, t1i = ai - ci;
            float t2r = br + dr, t2i = bi + di, t3r = br - dr, t3i = bi - di;
            s_re[i0] = t0r + t2r;  s_im[i0] = t0i + t2i;
            float B1r = t1r + t3i, B1i = t1i - t3r;     // t1 - i*t3
            float B2r = t0r - t2r, B2i = t0i - t2i;
            float B3r = t1r - t3i, B3i = t1i + t3r;     // t1 + i*t3
            s_re[i1] = B1r * w1r - B1i * w1i;  s_im[i1] = B1r * w1i + B1i * w1r;
            s_re[i2] = B2r * w2r - B2i * w2i;  s_im[i2] = B2r * w2i + B2i * w2r;
            s_re[i3] = B3r * w3r - B3i * w3i;  s_im[i3] = B3r * w3i + B3i * w3r;
        }
        __syncthreads();
    }
    // stage 5: L = 4, p = 0, all twiddles = 1
    #pragma unroll
    for (int u = 0; u < 4; ++u) {
        int base = (tid + u * NT) << 2;
        int i0 = swz(base), i1 = swz(base + 1), i2 = swz(base + 2), i3 = swz(base + 3);
        float ar = s_re[i0], ai = s_im[i0], br = s_re[i1], bi = s_im[i1];
        float cr = s_re[i2], ci = s_im[i2], dr = s_re[i3], di = s_im[i3];
        float t0r = ar + cr, t0i = ai + ci, t1r = ar - cr, t1i = ai - ci;
        float t2r = br + dr, t2i = bi + di, t3r = br - dr, t3i = bi - di;
        s_re[i0] = t0r + t2r;  s_im[i0] = t0i + t2i;
        s_re[i1] = t1r + t3i;  s_im[i1] = t1i - t3r;
        s_re[i2] = t0r - t2r;  s_im[i2] = t0i - t2i;
        s_re[i3] = t1r - t3i;  s_im[i3] = t1i + t3r;
    }
    __syncthreads();

    // per-thread register magnitudes of its 16 slots (j = tid + 256e);
    // true frequency k = rev4(j); only k <= N/2 are valid rfft bins.
    float mg[EPT];
    float lmax = -1.0f; int lk = 0x7fffffff;
    #pragma unroll
    for (int e = 0; e < EPT; ++e) {
        int j = tid + (e << 8);
        int k = rev4(j);
        int sj = swz(j);
        float rr = s_re[sj], ii = s_im[sj];
        float v = (k <= NN / 2) ? (rr * rr + ii * ii) : -1.0f;
        mg[e] = v;
        if (v > lmax || (v == lmax && k < lk)) { lmax = v; lk = k; }
    }

    // 16 rounds: block argmax over 256 cached per-thread maxima
    for (int r = 0; r < KTOP; ++r) {
        float bv = lmax; int bk = lk;
        #pragma unroll
        for (int off = 32; off > 0; off >>= 1) {
            float ov = __shfl_down(bv, off);
            int   ok = __shfl_down(bk, off);
            if (ov > bv || (ov == bv && ok < bk)) { bv = ov; bk = ok; }
        }
        if ((tid & 63) == 0) { s_rv[tid >> 6] = bv; s_rk[tid >> 6] = bk; }
        __syncthreads();
        bv = s_rv[0]; bk = s_rk[0];
        #pragma unroll
        for (int w2 = 1; w2 < NT / 64; ++w2) {
            float ov = s_rv[w2]; int ok = s_rk[w2];
            if (ov > bv || (ov == bv && ok < bk)) { bv = ov; bk = ok; }
        }
        if (lmax == bv && lk == bk) {        // unique winner (k owns one thread)
            int j = rev4(bk);                // storage slot of this frequency
            int sj = swz(j);
            s_kf[r] = bk; s_kr[r] = s_re[sj]; s_ki[r] = s_im[sj];
            int je = j >> 8;
            lmax = -1.0f; lk = 0x7fffffff;
            #pragma unroll
            for (int e = 0; e < EPT; ++e) {
                if (e == je) mg[e] = -1.0f;
                int kk = rev4(tid + (e << 8));
                float v = mg[e];
                if (v > lmax || (v == lmax && kk < lk)) { lmax = v; lk = kk; }
            }
        }
        __syncthreads();
    }

    // irfft of 16-bin spectrum; sin/cos from the LDS table (exact same values
    // the FFT used), half-circle + sign fix. Phase recurrence per freq.
    const int t0 = tid * EPT;
    float xf[EPT];
    #pragma unroll
    for (int i = 0; i < EPT; ++i) xf[i] = 0.0f;

    for (int r = 0; r < KTOP; ++r) {
        const int fj = s_kf[r];
        float vr = s_kr[r], vi = s_ki[r];
        if (fj == 0 || fj == NN / 2) { vi = 0.0f; }
        else { vr *= 2.0f; vi *= 2.0f; }
        const int ph0 = (fj * t0) & (NN - 1);
        int q0 = ph0 & (NN / 2 - 1);
        float tc = s_tw[swz(q0)], tsn = s_tw[swz(q0 + NN / 2)];
        float cr, ci;
        if (ph0 < NN / 2) { cr = tc;  ci = -tsn; }
        else              { cr = -tc; ci = tsn;  }
        int qs = fj & (NN / 2 - 1);
        float tc2 = s_tw[swz(qs)], tsn2 = s_tw[swz(qs + NN / 2)];
        float dc, ds;
        if (fj < NN / 2) { dc = tc2;  ds = -tsn2; }
        else             { dc = -tc2; ds = tsn2;  }
        #pragma unroll
        for (int i = 0; i < EPT; ++i) {
            xf[i] += vr * cr - vi * ci;
            float nc = cr * dc - ci * ds;
            ci = ci * dc + cr * ds;
            cr = nc;
        }
    }
    __syncthreads();     // last round's winner s_re reads are done

    #pragma unroll
    for (int i = 0; i < EPT; ++i)
        s_re[swz(t0 + i)] = xf[i] * (1.0f / (float)NN);
    __syncthreads();

    // flip-padded 25-tap correlation
    float win[EPT + WSZ - 1];
    #pragma unroll
    for (int i = 0; i < EPT + WSZ - 1; ++i) {
        int a = t0 + i - HALFW;
        if (a < 0)        a = -1 - a;
        else if (a >= NN) a = 2 * NN - 1 - a;
        win[i] = s_re[swz(a)];
    }

    const float rinv = 1.0f / s_wsum;
    float acc[EPT];
    #pragma unroll
    for (int t = 0; t < EPT; ++t) acc[t] = 0.0f;
    #pragma unroll
    for (int i = 0; i < WSZ; ++i) {
        const float wv = s_w[i];
        #pragma unroll
        for (int t = 0; t < EPT; ++t) acc[t] += win[t + i] * wv;
    }

    // stage in skewed LDS so the global write is float4-coalesced
    #pragma unroll
    for (int t = 0; t < EPT; ++t) s_im[swz(t0 + t)] = acc[t] * rinv;
    __syncthreads();

    float4* ch4w = (float4*)chan;
    #pragma unroll
    for (int i = 0; i < 4; ++i) {
        int a  = (tid + i * NT) * 4;
        int sa = swz(a);
        float4 v = { s_im[sa], s_im[sa + 1], s_im[sa + 2], s_im[sa + 3] };
        ch4w[tid + i * NT] = v;
    }
}

// ---------------------------------------------------------------- fallback
// Round-1 single-kernel version (strided I/O), used only if ws is too small.
__global__ __launch_bounds__(NT, 3)
void spectral_filter_fallback(const float* __restrict__ x, float* __restrict__ out)
{
    __shared__ float s_re[NN + (NN >> 5)];
    __shared__ float s_im[NN];
    __shared__ float s_tw[NN];
    __shared__ float s_w[WSZ];
    __shared__ float s_wsum;
    __shared__ float s_rv[NT / 64];
    __shared__ int   s_ri[NT / 64];
    __shared__ int   s_kf[KTOP];
    __shared__ float s_kr[KTOP];
    __shared__ float s_ki[KTOP];

    const int tid = threadIdx.x;
    const int c   = blockIdx.x;
    const int b   = c >> 7;
    const int f   = c & (FDIM - 1);
    const size_t base = (size_t)b * NN * FDIM + f;

    if (tid < WSZ)
        s_w[tid] = 0.54f - 0.46f * cosf(TWO_PI * (float)tid / (float)WSZ);

    for (int i = tid; i < NN / 2; i += NT) {
        float sn, cs;
        sincosf(-TWO_PI * (float)i / (float)NN, &sn, &cs);
        s_tw[i]          = cs;
        s_tw[i + NN / 2] = sn;
    }

    #pragma unroll
    for (int i = 0; i < EPT; ++i) {
        int j = tid + i * NT;
        int t = (int)(__brev((unsigned)j) >> (32 - LOGN));
        s_re[j] = x[base + (size_t)t * FDIM];
        s_im[j] = 0.0f;
    }
    __syncthreads();

    if (tid == 0) {
        float a = 0.0f;
        for (int i = 0; i < WSZ; ++i) a += s_w[i];
        s_wsum = a;
    }

    for (int s = 1; s <= LOGN; ++s) {
        const int half = 1 << (s - 1);
        const int tsh  = LOGN - s;
        #pragma unroll
        for (int i = 0; i < EPT / 2; ++i) {
            int j  = tid + i * NT;
            int p  = j & (half - 1);
            int i0 = ((j >> (s - 1)) << s) + p;
            int i1 = i0 + half;
            int q  = p << tsh;
            float wr = s_tw[q], wi = s_tw[q + NN / 2];
            float ar = s_re[i0], ai = s_im[i0];
            float br = s_re[i1], bi = s_im[i1];
            float tr = br * wr - bi * wi;
            float ti = br * wi + bi * wr;
            s_re[i0] = ar + tr;  s_im[i0] = ai + ti;
            s_re[i1] = ar - tr;  s_im[i1] = ai - ti;
        }
        __syncthreads();
    }

    for (int i = tid; i < NN / 2 + 1; i += NT) {
        float rr = s_re[i], ii = s_im[i];
        s_tw[i] = rr * rr + ii * ii;
    }
    __syncthreads();

    for (int r = 0; r < KTOP; ++r) {
        float best = -1.0f; int bidx = 0x7fffffff;
        for (int i = tid; i < NN / 2 + 1; i += NT) {
            float v = s_tw[i];
            if (v > best) { best = v; bidx = i; }
        }
        #pragma unroll
        for (int off = 32; off > 0; off >>= 1) {
            float ov = __shfl_down(best, off);
            int   oi = __shfl_down(bidx, off);
            if (ov > best || (ov == best && oi < bidx)) { best = ov; bidx = oi; }
        }
        const int wid = tid >> 6;
        if ((tid & 63) == 0) { s_rv[wid] = best; s_ri[wid] = bidx; }
        __syncthreads();
        if (tid == 0) {
            float bv = s_rv[0]; int bx = s_ri[0];
            #pragma unroll
            for (int w2 = 1; w2 < NT / 64; ++w2) {
                float ov = s_rv[w2]; int oi = s_ri[w2];
                if (ov > bv || (ov == bv && oi < bx)) { bv = ov; bx = oi; }
            }
            s_kf[r] = bx;
            s_kr[r] = s_re[bx];
            s_ki[r] = s_im[bx];
            s_tw[bx] = -1.0f;
        }
        __syncthreads();
    }

    const int t0 = tid * EPT;
    float xf[EPT];
    #pragma unroll
    for (int i = 0; i < EPT; ++i) xf[i] = 0.0f;

    for (int r = 0; r < KTOP; ++r) {
        const int fj = s_kf[r];
        float vr = s_kr[r], vi = s_ki[r];
        float sc = 2.0f;
        if (fj == 0 || fj == NN / 2) { sc = 1.0f; vi = 0.0f; }
        vr *= sc; vi *= sc;
        const int ph0 = (fj * t0) & (NN - 1);
        float c0, s0, dc, ds;
        sincosf((float)ph0 * (TWO_PI / (float)NN), &s0, &c0);
        sincosf((float)fj  * (TWO_PI / (float)NN), &ds, &dc);
        float cr = c0, ci = s0;
        #pragma unroll
        for (int i = 0; i < EPT; ++i) {
            xf[i] += vr * cr - vi * ci;
            float nc = cr * dc - ci * ds;
            ci = ci * dc + cr * ds;
            cr = nc;
        }
    }
    __syncthreads();

    #pragma unroll
    for (int i = 0; i < EPT; ++i)
        s_re[swz(t0 + i)] = xf[i] * (1.0f / (float)NN);
    __syncthreads();

    float win[EPT + WSZ - 1];
    #pragma unroll
    for (int i = 0; i < EPT + WSZ - 1; ++i) {
        int a = t0 + i - HALFW;
        if (a < 0)        a = -1 - a;
        else if (a >= NN) a = 2 * NN - 1 - a;
        win[i] = s_re[swz(a)];
    }

    const float rinv = 1.0f / s_wsum;
    float acc[EPT];
    #pragma unroll
    for (int t = 0; t < EPT; ++t) acc[t] = 0.0f;
    #pragma unroll
    for (int i = 0; i < WSZ; ++i) {
        const float wv = s_w[i];
        #pragma unroll
        for (int t = 0; t < EPT; ++t) acc[t] += win[t + i] * wv;
    }
    #pragma unroll
    for (int t = 0; t < EPT; ++t)
        out[base + (size_t)(t0 + t) * FDIM] = acc[t] * rinv;
}

extern "C" void kernel_launch(void* const* d_in, const int* in_sizes, int n_in,
                              void* d_out, int out_size, void* d_ws, size_t ws_size,
                              hipStream_t stream)
{
    const float* x = (const float*)d_in[0];
    float* out = (float*)d_out;
    const size_t need = (size_t)BATCH * FDIM * NN * sizeof(float);
    if (ws_size >= need) {
        float* ws = (float*)d_ws;
        // K1: x (B, T=4096, F=128) -> ws (B, F, T)
        transpose_kernel<<<dim3(FDIM / 64, NN / 64, BATCH), 256, 0, stream>>>(x, ws, NN, FDIM);
        // K2: per-channel pipeline, in place on ws
        spectral_fft_kernel<<<dim3(BATCH * FDIM), NT, 0, stream>>>(ws);
        // K3: ws (B, F=128, T=4096) -> out (B, T, F)
        transpose_kernel<<<dim3(NN / 64, FDIM / 64, BATCH), 256, 0, stream>>>(ws, out, FDIM, NN);
    } else {
        spectral_filter_fallback<<<dim3(BATCH * FDIM), NT, 0, stream>>>(x, out);
    }
}

// Round 4
// 317.868 us; speedup vs baseline: 1.9077x; 1.2403x over previous
//
#include <hip/hip_runtime.h>
#include <math.h>

// Spectral_Filter_Transform: per-channel rfft -> keep top-16 |X| bins -> irfft
// (= sum of 16 cosines) -> flip-pad 12 -> 25-tap periodic-Hamming average.
//
// 3-kernel pipeline:
//   K1: transpose x (B,T,F) -> ws (B,F,T)
//   K2: per-channel radix-16^3 register FFT + register top-k + recon + conv
//   K3: transpose ws (B,F,T) -> out (B,T,F)
// Fallback single-kernel version if ws is too small.

#define NN     4096
#define LOGN   12
#define NT     256
#define EPT    16      // NN / NT
#define KTOP   16
#define WSZ    25
#define HALFW  12
#define FDIM   128
#define BATCH  32
#define TWO_PI 6.283185307179586f

// skew: spreads power-of-2 LDS strides across banks; preserves float4 groups.
__device__ __forceinline__ int swz(int a) { return a + (a >> 5); }

#define CMUL(r, i, wr_, wi_) { float _r = (r); (r) = _r * (wr_) - (i) * (wi_); (i) = _r * (wi_) + (i) * (wr_); }
#define MULNI(r, i)          { float _r = (r); (r) = (i); (i) = -_r; }   // *(-i)

// 16-point forward DFT (W16 = e^{-2pi i/16}) fully in registers, natural order.
// Decomposed 4x4: step A radix-4 over n1, step B W16^{k1*n2}, step C radix-4 over n2.
__device__ __forceinline__ void dft16(float (&zr)[16], float (&zi)[16])
{
    const float C1 = 0.92387953251128674f;   // cos(pi/8)
    const float S1 = 0.38268343236508978f;   // sin(pi/8)
    const float R2 = 0.70710678118654752f;   // sqrt(2)/2
    float yr[16], yi[16];
    #pragma unroll
    for (int n2 = 0; n2 < 4; ++n2) {
        float ar = zr[n2],      ai = zi[n2];
        float br = zr[4 + n2],  bi = zi[4 + n2];
        float cr = zr[8 + n2],  ci = zi[8 + n2];
        float dr = zr[12 + n2], di = zi[12 + n2];
        float t0r = ar + cr, t0i = ai + ci;
        float t1r = ar - cr, t1i = ai - ci;
        float t2r = br + dr, t2i = bi + di;
        float t3r = br - dr, t3i = bi - di;
        yr[n2]      = t0r + t2r;  yi[n2]      = t0i + t2i;   // k1=0
        yr[4 + n2]  = t1r + t3i;  yi[4 + n2]  = t1i - t3r;   // k1=1  (t1 - i t3)
        yr[8 + n2]  = t0r - t2r;  yi[8 + n2]  = t0i - t2i;   // k1=2
        yr[12 + n2] = t1r - t3i;  yi[12 + n2] = t1i + t3r;   // k1=3  (t1 + i t3)
    }
    // step B: y[k1*4+n2] *= W16^{k1*n2}
    CMUL(yr[5],  yi[5],  C1, -S1);    // W^1
    CMUL(yr[6],  yi[6],  R2, -R2);    // W^2
    CMUL(yr[7],  yi[7],  S1, -C1);    // W^3
    CMUL(yr[9],  yi[9],  R2, -R2);    // W^2
    MULNI(yr[10], yi[10]);            // W^4 = -i
    CMUL(yr[11], yi[11], -R2, -R2);   // W^6
    CMUL(yr[13], yi[13], S1, -C1);    // W^3
    CMUL(yr[14], yi[14], -R2, -R2);   // W^6
    CMUL(yr[15], yi[15], -C1, S1);    // W^9
    // step C: radix-4 over n2 within each k1 row; X[4k2+k1] (natural order)
    #pragma unroll
    for (int k1 = 0; k1 < 4; ++k1) {
        float ar = yr[k1 * 4 + 0], ai = yi[k1 * 4 + 0];
        float br = yr[k1 * 4 + 1], bi = yi[k1 * 4 + 1];
        float cr = yr[k1 * 4 + 2], ci = yi[k1 * 4 + 2];
        float dr = yr[k1 * 4 + 3], di = yi[k1 * 4 + 3];
        float t0r = ar + cr, t0i = ai + ci;
        float t1r = ar - cr, t1i = ai - ci;
        float t2r = br + dr, t2i = bi + di;
        float t3r = br - dr, t3i = bi - di;
        zr[k1]      = t0r + t2r;  zi[k1]      = t0i + t2i;
        zr[4 + k1]  = t1r + t3i;  zi[4 + k1]  = t1i - t3r;
        zr[8 + k1]  = t0r - t2r;  zi[8 + k1]  = t0i - t2i;
        zr[12 + k1] = t1r - t3i;  zi[12 + k1] = t1i + t3r;
    }
}

// ---------------------------------------------------------------- transpose
__global__ __launch_bounds__(256)
void transpose_kernel(const float* __restrict__ in, float* __restrict__ out,
                      int R, int C)
{
    __shared__ float tile[64][65];
    const int b = blockIdx.z;
    const float* pin  = in  + (size_t)b * R * C;
    float*       pout = out + (size_t)b * R * C;
    const int r0 = blockIdx.y * 64, c0 = blockIdx.x * 64;
    const int tc4 = (threadIdx.x & 15) * 4;
    const int tr  = threadIdx.x >> 4;
    #pragma unroll
    for (int i = 0; i < 4; ++i) {
        int r = tr + i * 16;
        float4 v = *(const float4*)&pin[(size_t)(r0 + r) * C + c0 + tc4];
        tile[r][tc4 + 0] = v.x; tile[r][tc4 + 1] = v.y;
        tile[r][tc4 + 2] = v.z; tile[r][tc4 + 3] = v.w;
    }
    __syncthreads();
    #pragma unroll
    for (int i = 0; i < 4; ++i) {
        int r = tr + i * 16;
        float4 v;
        v.x = tile[tc4 + 0][r]; v.y = tile[tc4 + 1][r];
        v.z = tile[tc4 + 2][r]; v.w = tile[tc4 + 3][r];
        *(float4*)&pout[(size_t)(c0 + r) * R + r0 + tc4] = v;
    }
}

// ---------------------------------------------------------------- main kernel
__global__ __launch_bounds__(NT, 3)
void spectral_fft_kernel(float* __restrict__ ws)
{
    __shared__ float s_re[NN + (NN >> 5)];
    __shared__ float s_im[NN + (NN >> 5)];
    __shared__ float s_tw[NN + (NN >> 5)];   // cos(2πq/N) @swz(q), -sin @swz(q+2048)
    __shared__ float s_w[WSZ];
    __shared__ float s_wsum;
    __shared__ float s_rv[8];
    __shared__ int   s_rk[8];
    __shared__ int   s_kf[KTOP];
    __shared__ float s_kr[KTOP];
    __shared__ float s_ki[KTOP];

    const int tid = threadIdx.x;
    float* chan = ws + (size_t)blockIdx.x * NN;

    if (tid < WSZ)
        s_w[tid] = 0.54f - 0.46f * cosf(TWO_PI * (float)tid / (float)WSZ);

    // global load first (latency hides under table build): stride-256 ownership,
    // wave-level fully coalesced (64 consecutive dwords per load).
    float zr[16], zi[16];
    #pragma unroll
    for (int r = 0; r < 16; ++r) { zr[r] = chan[tid + (r << 8)]; zi[r] = 0.0f; }

    for (int i = tid; i < NN / 2; i += NT) {
        float sn, cs;
        sincosf(-TWO_PI * (float)i / (float)NN, &sn, &cs);
        s_tw[swz(i)]          = cs;
        s_tw[swz(i + NN / 2)] = sn;
    }

    // ---- stage 0 (L=4096): 16-pt DFT in registers (no table needed yet)
    dft16(zr, zi);
    __syncthreads();                 // twiddle table ready

    if (tid == 0) {                  // sequential fp32 sum, matching jnp.sum(w)
        float a = 0.0f;
        for (int i = 0; i < WSZ; ++i) a += s_w[i];
        s_wsum = a;
    }

    {   // twiddle W_4096^{tid*u} via seed + rotation; scatter to LDS at tid+256u
        float dr = s_tw[swz(tid)], di = s_tw[swz(tid + 2048)];
        float wr = dr, wi = di;
        #pragma unroll
        for (int u = 1; u < 16; ++u) {
            CMUL(zr[u], zi[u], wr, wi);
            float nr = wr * dr - wi * di; wi = wr * di + wi * dr; wr = nr;
        }
        #pragma unroll
        for (int u = 0; u < 16; ++u) {
            int a = swz(tid + (u << 8));
            s_re[a] = zr[u]; s_im[a] = zi[u];
        }
    }
    __syncthreads();

    {   // ---- stage 1 (L=256): segment g=tid>>4, offset p=tid&15
        const int p = tid & 15;
        const int b0 = ((tid >> 4) << 8) + p;
        #pragma unroll
        for (int r = 0; r < 16; ++r) {
            int a = swz(b0 + (r << 4));
            zr[r] = s_re[a]; zi[r] = s_im[a];
        }
        dft16(zr, zi);
        float dr = s_tw[swz(p << 4)], di = s_tw[swz((p << 4) + 2048)];
        float wr = dr, wi = di;
        #pragma unroll
        for (int u = 1; u < 16; ++u) {
            CMUL(zr[u], zi[u], wr, wi);
            float nr = wr * dr - wi * di; wi = wr * di + wi * dr; wr = nr;
        }
        #pragma unroll
        for (int u = 0; u < 16; ++u) {
            int a = swz(b0 + (u << 4));
            s_re[a] = zr[u]; s_im[a] = zi[u];
        }
    }
    __syncthreads();

    {   // ---- stage 2 (L=16): contiguous 16, no twiddles; results stay in regs
        #pragma unroll
        for (int r = 0; r < 16; ++r) {
            int a = swz((tid << 4) + r);
            zr[r] = s_re[a]; zi[r] = s_im[a];
        }
        dft16(zr, zi);
    }

    // thread tid's result u is true bin f = 256*u + fbase, fbase = nibbleswap(tid).
    // Valid rfft bins: u<8 always; u==8 only for tid==0 (f=2048=Nyquist).
    const int fbase = ((tid & 15) << 4) | (tid >> 4);
    float mg[9];
    float lmax = -1.0f; int lk = 0x7fffffff;
    #pragma unroll
    for (int u = 0; u < 9; ++u) {
        float v = zr[u] * zr[u] + zi[u] * zi[u];
        if (u == 8 && fbase != 0) v = -1.0f;
        mg[u] = v;
        if (v > lmax) { lmax = v; lk = (u << 8) + fbase; }  // ascending f: > keeps lowest
    }

    // 16 rounds of block argmax over 256 cached per-thread maxima
    for (int r = 0; r < KTOP; ++r) {
        float bv = lmax; int bk = lk;
        #pragma unroll
        for (int off = 32; off > 0; off >>= 1) {
            float ov = __shfl_down(bv, off);
            int   ok = __shfl_down(bk, off);
            if (ov > bv || (ov == bv && ok < bk)) { bv = ov; bk = ok; }
        }
        const int buf = (r & 1) << 2;
        if ((tid & 63) == 0) { s_rv[buf + (tid >> 6)] = bv; s_rk[buf + (tid >> 6)] = bk; }
        __syncthreads();
        bv = s_rv[buf]; bk = s_rk[buf];
        #pragma unroll
        for (int w2 = 1; w2 < 4; ++w2) {
            float ov = s_rv[buf + w2]; int ok = s_rk[buf + w2];
            if (ov > bv || (ov == bv && ok < bk)) { bv = ov; bk = ok; }
        }
        if (lmax == bv && lk == bk) {      // unique winner thread
            const int uw = bk >> 8;
            s_kf[r] = bk;
            #pragma unroll
            for (int u2 = 0; u2 < 9; ++u2) {       // predicated selects, no dyn index
                if (u2 == uw) { s_kr[r] = zr[u2]; s_ki[r] = zi[u2]; mg[u2] = -1.0f; }
            }
            lmax = -1.0f; lk = 0x7fffffff;
            #pragma unroll
            for (int u2 = 0; u2 < 9; ++u2) {
                float v = mg[u2];
                if (v > lmax) { lmax = v; lk = (u2 << 8) + fbase; }
            }
        }
    }
    __syncthreads();    // s_kf/s_kr/s_ki of the last round visible to all

    // irfft of 16-bin spectrum; sin/cos seeds from the LDS table, rotation after.
    const int t0 = tid * EPT;
    float xf[EPT];
    #pragma unroll
    for (int i = 0; i < EPT; ++i) xf[i] = 0.0f;

    for (int r = 0; r < KTOP; ++r) {
        const int fj = s_kf[r];
        float vr = s_kr[r], vi = s_ki[r];
        if (fj == 0 || fj == NN / 2) { vi = 0.0f; }
        else { vr *= 2.0f; vi *= 2.0f; }
        const int ph0 = (fj * t0) & (NN - 1);
        int q0 = ph0 & (NN / 2 - 1);
        float tc = s_tw[swz(q0)], tsn = s_tw[swz(q0 + NN / 2)];
        float cr, ci;
        if (ph0 < NN / 2) { cr = tc;  ci = -tsn; }
        else              { cr = -tc; ci = tsn;  }
        int qs = fj & (NN / 2 - 1);
        float tc2 = s_tw[swz(qs)], tsn2 = s_tw[swz(qs + NN / 2)];
        float dc, ds;
        if (fj < NN / 2) { dc = tc2;  ds = -tsn2; }
        else             { dc = -tc2; ds = tsn2;  }
        #pragma unroll
        for (int i = 0; i < EPT; ++i) {
            xf[i] += vr * cr - vi * ci;
            float nc = cr * dc - ci * ds;
            ci = ci * dc + cr * ds;
            cr = nc;
        }
    }

    #pragma unroll
    for (int i = 0; i < EPT; ++i)
        s_re[swz(t0 + i)] = xf[i] * (1.0f / (float)NN);
    __syncthreads();

    // flip-padded 25-tap correlation
    float win[EPT + WSZ - 1];
    #pragma unroll
    for (int i = 0; i < EPT + WSZ - 1; ++i) {
        int a = t0 + i - HALFW;
        if (a < 0)        a = -1 - a;
        else if (a >= NN) a = 2 * NN - 1 - a;
        win[i] = s_re[swz(a)];
    }

    const float rinv = 1.0f / s_wsum;
    float acc[EPT];
    #pragma unroll
    for (int t = 0; t < EPT; ++t) acc[t] = 0.0f;
    #pragma unroll
    for (int i = 0; i < WSZ; ++i) {
        const float wv = s_w[i];
        #pragma unroll
        for (int t = 0; t < EPT; ++t) acc[t] += win[t + i] * wv;
    }

    // stage in skewed LDS so the global write is float4-coalesced
    #pragma unroll
    for (int t = 0; t < EPT; ++t) s_im[swz(t0 + t)] = acc[t] * rinv;
    __syncthreads();

    float4* ch4w = (float4*)chan;
    #pragma unroll
    for (int i = 0; i < 4; ++i) {
        int a  = (tid + i * NT) * 4;
        int sa = swz(a);
        float4 v = { s_im[sa], s_im[sa + 1], s_im[sa + 2], s_im[sa + 3] };
        ch4w[tid + i * NT] = v;
    }
}

// ---------------------------------------------------------------- fallback
__global__ __launch_bounds__(NT, 3)
void spectral_filter_fallback(const float* __restrict__ x, float* __restrict__ out)
{
    __shared__ float s_re[NN + (NN >> 5)];
    __shared__ float s_im[NN];
    __shared__ float s_tw[NN];
    __shared__ float s_w[WSZ];
    __shared__ float s_wsum;
    __shared__ float s_rv[NT / 64];
    __shared__ int   s_ri[NT / 64];
    __shared__ int   s_kf[KTOP];
    __shared__ float s_kr[KTOP];
    __shared__ float s_ki[KTOP];

    const int tid = threadIdx.x;
    const int c   = blockIdx.x;
    const int b   = c >> 7;
    const int f   = c & (FDIM - 1);
    const size_t base = (size_t)b * NN * FDIM + f;

    if (tid < WSZ)
        s_w[tid] = 0.54f - 0.46f * cosf(TWO_PI * (float)tid / (float)WSZ);

    for (int i = tid; i < NN / 2; i += NT) {
        float sn, cs;
        sincosf(-TWO_PI * (float)i / (float)NN, &sn, &cs);
        s_tw[i]          = cs;
        s_tw[i + NN / 2] = sn;
    }

    #pragma unroll
    for (int i = 0; i < EPT; ++i) {
        int j = tid + i * NT;
        int t = (int)(__brev((unsigned)j) >> (32 - LOGN));
        s_re[j] = x[base + (size_t)t * FDIM];
        s_im[j] = 0.0f;
    }
    __syncthreads();

    if (tid == 0) {
        float a = 0.0f;
        for (int i = 0; i < WSZ; ++i) a += s_w[i];
        s_wsum = a;
    }

    for (int s = 1; s <= LOGN; ++s) {
        const int half = 1 << (s - 1);
        const int tsh  = LOGN - s;
        #pragma unroll
        for (int i = 0; i < EPT / 2; ++i) {
            int j  = tid + i * NT;
            int p  = j & (half - 1);
            int i0 = ((j >> (s - 1)) << s) + p;
            int i1 = i0 + half;
            int q  = p << tsh;
            float wr = s_tw[q], wi = s_tw[q + NN / 2];
            float ar = s_re[i0], ai = s_im[i0];
            float br = s_re[i1], bi = s_im[i1];
            float tr = br * wr - bi * wi;
            float ti = br * wi + bi * wr;
            s_re[i0] = ar + tr;  s_im[i0] = ai + ti;
            s_re[i1] = ar - tr;  s_im[i1] = ai - ti;
        }
        __syncthreads();
    }

    for (int i = tid; i < NN / 2 + 1; i += NT) {
        float rr = s_re[i], ii = s_im[i];
        s_tw[i] = rr * rr + ii * ii;
    }
    __syncthreads();

    for (int r = 0; r < KTOP; ++r) {
        float best = -1.0f; int bidx = 0x7fffffff;
        for (int i = tid; i < NN / 2 + 1; i += NT) {
            float v = s_tw[i];
            if (v > best) { best = v; bidx = i; }
        }
        #pragma unroll
        for (int off = 32; off > 0; off >>= 1) {
            float ov = __shfl_down(best, off);
            int   oi = __shfl_down(bidx, off);
            if (ov > best || (ov == best && oi < bidx)) { best = ov; bidx = oi; }
        }
        const int wid = tid >> 6;
        if ((tid & 63) == 0) { s_rv[wid] = best; s_ri[wid] = bidx; }
        __syncthreads();
        if (tid == 0) {
            float bv = s_rv[0]; int bx = s_ri[0];
            #pragma unroll
            for (int w2 = 1; w2 < NT / 64; ++w2) {
                float ov = s_rv[w2]; int oi = s_ri[w2];
                if (ov > bv || (ov == bv && oi < bx)) { bv = ov; bx = oi; }
            }
            s_kf[r] = bx;
            s_kr[r] = s_re[bx];
            s_ki[r] = s_im[bx];
            s_tw[bx] = -1.0f;
        }
        __syncthreads();
    }

    const int t0 = tid * EPT;
    float xf[EPT];
    #pragma unroll
    for (int i = 0; i < EPT; ++i) xf[i] = 0.0f;

    for (int r = 0; r < KTOP; ++r) {
        const int fj = s_kf[r];
        float vr = s_kr[r], vi = s_ki[r];
        float sc = 2.0f;
        if (fj == 0 || fj == NN / 2) { sc = 1.0f; vi = 0.0f; }
        vr *= sc; vi *= sc;
        const int ph0 = (fj * t0) & (NN - 1);
        float c0, s0, dc, ds;
        sincosf((float)ph0 * (TWO_PI / (float)NN), &s0, &c0);
        sincosf((float)fj  * (TWO_PI / (float)NN), &ds, &dc);
        float cr = c0, ci = s0;
        #pragma unroll
        for (int i = 0; i < EPT; ++i) {
            xf[i] += vr * cr - vi * ci;
            float nc = cr * dc - ci * ds;
            ci = ci * dc + cr * ds;
            cr = nc;
        }
    }
    __syncthreads();

    #pragma unroll
    for (int i = 0; i < EPT; ++i)
        s_re[swz(t0 + i)] = xf[i] * (1.0f / (float)NN);
    __syncthreads();

    float win[EPT + WSZ - 1];
    #pragma unroll
    for (int i = 0; i < EPT + WSZ - 1; ++i) {
        int a = t0 + i - HALFW;
        if (a < 0)        a = -1 - a;
        else if (a >= NN) a = 2 * NN - 1 - a;
        win[i] = s_re[swz(a)];
    }

    const float rinv = 1.0f / s_wsum;
    float acc[EPT];
    #pragma unroll
    for (int t = 0; t < EPT; ++t) acc[t] = 0.0f;
    #pragma unroll
    for (int i = 0; i < WSZ; ++i) {
        const float wv = s_w[i];
        #pragma unroll
        for (int t = 0; t < EPT; ++t) acc[t] += win[t + i] * wv;
    }
    #pragma unroll
    for (int t = 0; t < EPT; ++t)
        out[base + (size_t)(t0 + t) * FDIM] = acc[t] * rinv;
}

extern "C" void kernel_launch(void* const* d_in, const int* in_sizes, int n_in,
                              void* d_out, int out_size, void* d_ws, size_t ws_size,
                              hipStream_t stream)
{
    const float* x = (const float*)d_in[0];
    float* out = (float*)d_out;
    const size_t need = (size_t)BATCH * FDIM * NN * sizeof(float);
    if (ws_size >= need) {
        float* ws = (float*)d_ws;
        transpose_kernel<<<dim3(FDIM / 64, NN / 64, BATCH), 256, 0, stream>>>(x, ws, NN, FDIM);
        spectral_fft_kernel<<<dim3(BATCH * FDIM), NT, 0, stream>>>(ws);
        transpose_kernel<<<dim3(NN / 64, FDIM / 64, BATCH), 256, 0, stream>>>(ws, out, FDIM, NN);
    } else {
        spectral_filter_fallback<<<dim3(BATCH * FDIM), NT, 0, stream>>>(x, out);
    }
}